// Round 14
// baseline (1181.165 us; speedup 1.0000x reference)
//
#include <hip/hip_runtime.h>

#define Bz 32
#define Tz 200
#define Rz 8192
#define Kz 409
#define KP 416
#define K2 20
#define K2P 32
#define RESTz 7783

typedef __bf16 bf16x8 __attribute__((ext_vector_type(8)));
typedef float f32x4 __attribute__((ext_vector_type(4)));

// ---------------- pass 1: norms, scores, border mask (f32 out) ----------------
// R14: XLA-GPU column-reduction emulation. Both reduces over t use 32 strided
// partials (partial[y] = sum over t = y+32k, k ascending, rounded adds) combined
// by a binary tree (off = 16,8,4,2,1) — the shfl_down pattern. Elements:
// ss: fl(x*x);  score: fl(fl(x/nv)*w[t]); then one rounded +b_proj.
__launch_bounds__(256)
__global__ void k_stats(const float* __restrict__ x, const float* __restrict__ w_proj,
                        const float* __restrict__ b_proj,
                        float* __restrict__ invnrm, float* __restrict__ score,
                        int* __restrict__ bordany, float* __restrict__ border_out) {
    const int b = blockIdx.y;
    const int c = blockIdx.x * 256 + threadIdx.x;
    const float* xp = x + (size_t)b * Tz * Rz + c;
    float* bp = border_out + (size_t)b * Tz * Rz + c;
    float p[32];
#pragma unroll
    for (int y = 0; y < 32; ++y) p[y] = 0.f;
    int nn = 0;
    // pass A: ss partials + border writes
    for (int k = 0; k < 7; ++k) {
        const int tbase = k * 32;
#pragma unroll
        for (int y = 0; y < 32; ++y) {
            const int t = tbase + y;
            if (t < Tz) {
                float v = xp[(size_t)t * Rz];
                bool isn = (v != v);
                nn |= isn ? 1 : 0;
                float val = isn ? 0.f : v;
                bp[(size_t)t * Rz] = isn ? 1.0f : 0.0f;
                p[y] = __fadd_rn(p[y], __fmul_rn(val, val));
            }
        }
    }
#pragma unroll
    for (int off = 16; off > 0; off >>= 1)
#pragma unroll
        for (int y = 0; y < 16; ++y)
            if (y < off) p[y] = __fadd_rn(p[y], p[y + off]);
    const float ss = p[0];
    const float nv = fmaxf(__fsqrt_rn(ss), 1e-12f);
    // pass B: score partials, e = fl(fl(x/nv) * w[t]), plain adds
    float q[32];
#pragma unroll
    for (int y = 0; y < 32; ++y) q[y] = 0.f;
    for (int k = 0; k < 7; ++k) {
        const int tbase = k * 32;
#pragma unroll
        for (int y = 0; y < 32; ++y) {
            const int t = tbase + y;
            if (t < Tz) {
                float v = xp[(size_t)t * Rz];
                float val = (v != v) ? 0.f : v;
                float xn = __fdiv_rn(val, nv);
                float e = __fmul_rn(xn, w_proj[t]);
                q[y] = __fadd_rn(q[y], e);
            }
        }
    }
#pragma unroll
    for (int off = 16; off > 0; off >>= 1)
#pragma unroll
        for (int y = 0; y < 16; ++y)
            if (y < off) q[y] = __fadd_rn(q[y], q[y + off]);
    float sc = __fadd_rn(q[0], b_proj[0]);
    if (nn) sc = -10000.f;
    invnrm[(size_t)b * Rz + c] = __fdiv_rn(1.0f, nv);
    score[(size_t)b * Rz + c] = sc;
    bordany[(size_t)b * Rz + c] = nn;
}

// ---------------- top-k (radix select + bitonic order) + rest positions -------
// tie-break: (score desc, index ASC) — lax.top_k semantics.
__launch_bounds__(256)
__global__ void k_topk(const float* __restrict__ score, const int* __restrict__ bordany,
                       int* __restrict__ index_ws, int* __restrict__ rest_pos,
                       float* __restrict__ o_index) {
    const int b = blockIdx.x;
    const int tid = threadIdx.x;
    __shared__ unsigned su[Rz];
    __shared__ unsigned hist[256];
    __shared__ unsigned ckey[512];
    __shared__ unsigned cidx[512];
    __shared__ unsigned cnum;
    __shared__ unsigned sh_prefix;
    __shared__ int sh_need;
    __shared__ int scnt[256];

    for (int i = tid; i < Rz; i += 256) {
        unsigned u = __float_as_uint(score[(size_t)b * Rz + i]);
        u = (u & 0x80000000u) ? ~u : (u | 0x80000000u);
        su[i] = u;
    }
    __syncthreads();

    unsigned prefix = 0u, pmask = 0u;
    int need = Kz;
    for (int byte = 3; byte >= 0; --byte) {
        const int sh = byte * 8;
        hist[tid] = 0u;
        __syncthreads();
        for (int i = tid; i < Rz; i += 256) {
            unsigned u = su[i];
            if ((u & pmask) == prefix) atomicAdd(&hist[(u >> sh) & 255u], 1u);
        }
        __syncthreads();
        if (tid == 0) {
            int acc = 0, bsel = 255;
            for (int v = 255; v >= 0; --v) {
                int h = (int)hist[v];
                if (acc + h >= need) { bsel = v; break; }
                acc += h;
            }
            sh_need = need - acc;
            sh_prefix = prefix | ((unsigned)bsel << sh);
        }
        __syncthreads();
        prefix = sh_prefix;
        need = sh_need;
        pmask |= (0xFFu << sh);
        __syncthreads();
    }
    const unsigned Tval = prefix;

    if (tid == 0) cnum = 0u;
    __syncthreads();
    for (int i = tid; i < Rz; i += 256) {
        unsigned u = su[i];
        if (u >= Tval) {
            unsigned p = atomicAdd(&cnum, 1u);
            if (p < 512u) { ckey[p] = u; cidx[p] = (unsigned)i; }
        }
    }
    __syncthreads();
    const int cn = (cnum < 512u) ? (int)cnum : 512;
    for (int i = tid; i < 512; i += 256)
        if (i >= cn) { ckey[i] = 0u; cidx[i] = 0xFFFFFFFFu; }
    __syncthreads();

    // bitonic sort 512: (key desc, idx asc)
    for (int kk = 2; kk <= 512; kk <<= 1) {
        for (int j = kk >> 1; j > 0; j >>= 1) {
            const int i = ((tid & ~(j - 1)) << 1) | (tid & (j - 1));
            const int l = i | j;
            unsigned ka = ckey[i], kb = ckey[l];
            unsigned ia = cidx[i], ib = cidx[l];
            bool a_after_b = (ka < kb) || (ka == kb && ia > ib);
            bool b_after_a = (kb < ka) || (kb == ka && ib > ia);
            bool desc = ((i & kk) == 0);
            bool dosw = desc ? a_after_b : b_after_a;
            if (dosw) { ckey[i] = kb; ckey[l] = ka; cidx[i] = ib; cidx[l] = ia; }
            __syncthreads();
        }
    }

    for (int i = tid; i < Kz; i += 256) {
        int idx = (int)(cidx[i] & 8191u);
        index_ws[b * Kz + i] = idx;
        o_index[(size_t)b * Kz + i] = (float)idx;
    }
    __syncthreads();
    for (int i = tid; i < Rz; i += 256)
        su[i] = (bordany[(size_t)b * Rz + i] != 0) ? 1u : 0u;
    __syncthreads();
    for (int i = tid; i < Kz; i += 256) su[cidx[i] & 8191u] = 1u;
    __syncthreads();
    int cnt = 0;
    {
        const int base = tid * 32;
#pragma unroll
        for (int o = 0; o < 32; ++o) cnt += (su[base + o] == 0u) ? 1 : 0;
    }
    scnt[tid] = cnt;
    __syncthreads();
    for (int offp = 1; offp < 256; offp <<= 1) {
        int add = (tid >= offp) ? scnt[tid - offp] : 0;
        __syncthreads();
        scnt[tid] += add;
        __syncthreads();
    }
    const int total_un = scnt[255];
    int run = scnt[tid] - cnt;
    const int base = tid * 32;
    for (int o = 0; o < 32; ++o) {
        const int c = base + o;
        const bool un = (su[c] == 0u);
        int pos = un ? run : (total_un + (c - run));
        if (un) run++;
        if (pos < RESTz) rest_pos[b * RESTz + pos] = c;
    }
}

// ---------------- gather selected, normalized columns -> bf16 [6400][KP] ------
__launch_bounds__(256)
__global__ void k_gather(const float* __restrict__ x, const float* __restrict__ invnrm,
                         const int* __restrict__ index_ws, __bf16* __restrict__ x_topk) {
    const int m = blockIdx.x;
    const int b = m / Tz;
    const float* xrow = x + (size_t)m * Rz;
    for (int kk = threadIdx.x; kk < KP; kk += 256) {
        float val = 0.f;
        if (kk < Kz) {
            const unsigned idx = (unsigned)index_ws[b * Kz + kk] & 8191u;
            float v = xrow[idx];
            if (v != v) v = 0.f;
            val = __fmul_rn(v, invnrm[(size_t)b * Rz + idx]);
        }
        x_topk[(size_t)m * KP + kk] = (__bf16)val;
    }
}

// ---------------- BatchNorm over (b,k) per t (bf16 in, bf16 out) --------------
__launch_bounds__(256)
__global__ void k_bn(const __bf16* __restrict__ h, const float* __restrict__ gamma,
                     const float* __restrict__ beta, __bf16* __restrict__ hbn) {
    const int t = blockIdx.x;
    const int tid = threadIdx.x;
    float s = 0.f, s2 = 0.f;
    for (int i = tid; i < Bz * Kz; i += 256) {
        int b = i / Kz, j = i - b * Kz;
        float v = (float)h[(size_t)(b * Tz + t) * KP + j];
        s += v;
        s2 += v * v;
    }
    for (int off = 32; off > 0; off >>= 1) {
        s += __shfl_down(s, off);
        s2 += __shfl_down(s2, off);
    }
    __shared__ float rs[4], rs2[4];
    __shared__ float sc_sh, sf_sh;
    const int wid = tid >> 6;
    if ((tid & 63) == 0) { rs[wid] = s; rs2[wid] = s2; }
    __syncthreads();
    if (tid == 0) {
        float S = rs[0] + rs[1] + rs[2] + rs[3];
        float S2 = rs2[0] + rs2[1] + rs2[2] + rs2[3];
        const float invN = 1.f / (float)(Bz * Kz);
        float mu = S * invN;
        float var = S2 * invN - mu * mu;
        float rstd = rsqrtf(var + 1e-5f);
        float scl = gamma[t] * rstd;
        sc_sh = scl;
        sf_sh = beta[t] - mu * scl;
    }
    __syncthreads();
    const float scl = sc_sh, sft = sf_sh;
    for (int i = tid; i < Bz * KP; i += 256) {
        int b = i / KP, j = i - b * KP;
        float outv = 0.f;
        if (j < Kz) {
            float v = (float)h[(size_t)(b * Tz + t) * KP + j];
            outv = v * scl + sft;
        }
        hbn[(size_t)(b * Tz + t) * KP + j] = (__bf16)outv;
    }
}

// ---------------- dense mask writer (f32): mask[b,t,r] = sel[b][r] ------------
__launch_bounds__(256)
__global__ void k_mask(const int* __restrict__ index_ws, float* __restrict__ o_mask) {
    const int bt = blockIdx.x;
    const int b = bt / Tz;
    const int tid = threadIdx.x;
    __shared__ unsigned bm[256];
    bm[tid] = 0u;
    __syncthreads();
    for (int i = tid; i < Kz; i += 256) {
        unsigned idx = (unsigned)index_ws[b * Kz + i] & 8191u;
        atomicOr(&bm[idx >> 5], 1u << (idx & 31u));
    }
    __syncthreads();
    const unsigned bits = bm[tid];
    float* dst = o_mask + (size_t)bt * Rz + tid * 32;
#pragma unroll
    for (int g = 0; g < 8; ++g) {
        float4 v;
        v.x = ((bits >> (g * 4 + 0)) & 1u) ? 1.0f : 0.0f;
        v.y = ((bits >> (g * 4 + 1)) & 1u) ? 1.0f : 0.0f;
        v.z = ((bits >> (g * 4 + 2)) & 1u) ? 1.0f : 0.0f;
        v.w = ((bits >> (g * 4 + 3)) & 1u) ? 1.0f : 0.0f;
        *(float4*)(dst + g * 4) = v;
    }
}

// ---- MFMA GEMM, B staged directly from f32 weights [Nreal][Kreal] (guarded) ----
template <int EPI>
__launch_bounds__(256)
__global__ void k_gemm(const __bf16* __restrict__ A, int lda, int ksteps,
                       const float* __restrict__ Wf, int Nreal, int Kreal,
                       const float* __restrict__ bias,
                       __bf16* __restrict__ b_out,
                       float* __restrict__ o_xc,
                       const int* __restrict__ index_ws,
                       const int* __restrict__ rest_pos,
                       float* __restrict__ o_recon) {
    __shared__ __bf16 As[64][48];
    __shared__ __bf16 Bs[64][48];
    const int m0 = blockIdx.x * 64;
    const int n0 = blockIdx.y * 64;
    const int tid = threadIdx.x;
    const int lane = tid & 63;
    const int wid = tid >> 6;
    const int wm = wid >> 1, wn = wid & 1;
    const int srow = tid >> 2;
    const int skp = (tid & 3) * 8;
    const int fr = lane & 15;
    const int fg = lane >> 4;
    f32x4 acc[2][2];
#pragma unroll
    for (int i = 0; i < 2; ++i)
#pragma unroll
        for (int j = 0; j < 2; ++j) {
            f32x4 z = {0.f, 0.f, 0.f, 0.f};
            acc[i][j] = z;
        }

    const int brow = n0 + srow;
    const bool rok = brow < Nreal;
    const float* wrow = Wf + (size_t)brow * Kreal;

    for (int s = 0; s < ksteps; ++s) {
        const int k0 = s * 32;
        bf16x8 av = *(const bf16x8*)(A + (size_t)(m0 + srow) * lda + (k0 + skp));
        bf16x8 bv;
#pragma unroll
        for (int e = 0; e < 8; ++e) {
            const int c = k0 + skp + e;
            bv[e] = (__bf16)((rok && c < Kreal) ? wrow[c] : 0.f);
        }
        __syncthreads();
        *(bf16x8*)&As[srow][skp] = av;
        *(bf16x8*)&Bs[srow][skp] = bv;
        __syncthreads();
        bf16x8 a0 = *(const bf16x8*)&As[wm * 32 + fr][fg * 8];
        bf16x8 a1 = *(const bf16x8*)&As[wm * 32 + 16 + fr][fg * 8];
        bf16x8 b0 = *(const bf16x8*)&Bs[wn * 32 + fr][fg * 8];
        bf16x8 b1 = *(const bf16x8*)&Bs[wn * 32 + 16 + fr][fg * 8];
        acc[0][0] = __builtin_amdgcn_mfma_f32_16x16x32_bf16(a0, b0, acc[0][0], 0, 0, 0);
        acc[0][1] = __builtin_amdgcn_mfma_f32_16x16x32_bf16(a0, b1, acc[0][1], 0, 0, 0);
        acc[1][0] = __builtin_amdgcn_mfma_f32_16x16x32_bf16(a1, b0, acc[1][0], 0, 0, 0);
        acc[1][1] = __builtin_amdgcn_mfma_f32_16x16x32_bf16(a1, b1, acc[1][1], 0, 0, 0);
    }

#pragma unroll
    for (int mi = 0; mi < 2; ++mi)
#pragma unroll
        for (int ni = 0; ni < 2; ++ni)
#pragma unroll
            for (int rr = 0; rr < 4; ++rr) {
                const int gm = m0 + wm * 32 + mi * 16 + fg * 4 + rr;
                const int gn = n0 + wn * 32 + ni * 16 + fr;
                const float v = acc[mi][ni][rr];
                if constexpr (EPI == 0) {
                    if (gn < KP) {
                        float val = (gn < Kz) ? (v + bias[gn]) : 0.f;
                        b_out[(size_t)gm * KP + gn] = (__bf16)val;
                    }
                } else if constexpr (EPI == 1) {
                    if (gn < K2P) {
                        float val = (gn < K2) ? (v + bias[gn]) : 0.f;
                        if (gn < K2) o_xc[(size_t)gm * K2 + gn] = val;
                        b_out[(size_t)gm * K2P + gn] = (__bf16)val;
                    }
                } else if constexpr (EPI == 2) {
                    if (gn < KP) {
                        float val = (gn < Kz) ? (v + bias[gn]) : 0.f;
                        b_out[(size_t)gm * KP + gn] = (__bf16)val;
                    }
                } else if constexpr (EPI == 3) {
                    if (gn < KP) {
                        float val = (gn < Kz) ? (v + bias[gn]) : 0.f;
                        b_out[(size_t)gm * KP + gn] = (__bf16)val;
                        if (gn < Kz) {
                            const int bb = gm / Tz;
                            const unsigned col = (unsigned)index_ws[bb * Kz + gn] & 8191u;
                            o_recon[(size_t)gm * Rz + col] = val;
                        }
                    }
                } else {
                    if (gn < RESTz) {
                        const float val = v + bias[gn];
                        const int bb = gm / Tz;
                        const unsigned col = (unsigned)rest_pos[bb * RESTz + gn] & 8191u;
                        o_recon[(size_t)gm * Rz + col] = val;
                    }
                }
            }
}

extern "C" void kernel_launch(void* const* d_in, const int* in_sizes, int n_in,
                              void* d_out, int out_size, void* d_ws, size_t ws_size,
                              hipStream_t stream) {
    (void)in_sizes; (void)n_in; (void)out_size;
    const float* x           = (const float*)d_in[0];
    const float* w_proj      = (const float*)d_in[1];
    const float* b_proj      = (const float*)d_in[2];
    const float* w_process   = (const float*)d_in[3];
    const float* b_process   = (const float*)d_in[4];
    const float* bn_gamma    = (const float*)d_in[5];
    const float* bn_beta     = (const float*)d_in[6];
    const float* w_compress  = (const float*)d_in[7];
    const float* b_compress  = (const float*)d_in[8];
    const float* w_unzip     = (const float*)d_in[9];
    const float* b_unzip     = (const float*)d_in[10];
    const float* w_unprocess = (const float*)d_in[11];
    const float* b_unprocess = (const float*)d_in[12];
    const float* w_rest      = (const float*)d_in[13];
    const float* b_rest      = (const float*)d_in[14];

    float* out = (float*)d_out;
    float* o_recon  = out;
    float* o_xc     = o_recon + (size_t)Bz * Tz * Rz;
    float* o_mask   = o_xc + (size_t)Bz * Tz * K2;
    float* o_border = o_mask + (size_t)Bz * Tz * Rz;
    float* o_index  = o_border + (size_t)Bz * Tz * Rz;

    const size_t SLOT = ((size_t)Bz * Tz * KP * 2 + 255) & ~(size_t)255;
    const size_t IDXB = ((size_t)Bz * Kz * 4 + 255) & ~(size_t)255;
    const size_t RESB = ((size_t)Bz * RESTz * 4 + 255) & ~(size_t)255;
    const size_t need = 3 * SLOT + IDXB + RESB;
    if (ws_size < need) return;

    char* ws = (char*)d_ws;
    __bf16* S1 = (__bf16*)(ws);
    __bf16* S2 = (__bf16*)(ws + SLOT);
    __bf16* S3 = (__bf16*)(ws + 2 * SLOT);
    int* index_ws = (int*)(ws + 3 * SLOT);
    int* rest_pos = (int*)(ws + 3 * SLOT + IDXB);

    float* invnrm = (float*)S2;
    float* score  = invnrm + (size_t)Bz * Rz;
    int*   bordany = (int*)(score + (size_t)Bz * Rz);

    __bf16* x_topk = S1;
    __bf16* hbuf   = S2;
    __bf16* hbn    = S3;
    __bf16* xc_pad = S2;
    __bf16* z1     = S1;
    __bf16* zb     = S3;

    k_stats<<<dim3(Rz / 256, Bz), dim3(256), 0, stream>>>(x, w_proj, b_proj, invnrm, score,
                                                          bordany, o_border);
    k_topk<<<dim3(Bz), dim3(256), 0, stream>>>(score, bordany, index_ws, rest_pos, o_index);
    k_gather<<<dim3(Bz * Tz), dim3(256), 0, stream>>>(x, invnrm, index_ws, x_topk);

    dim3 blk(256);
    k_gemm<0><<<dim3(100, 7), blk, 0, stream>>>(x_topk, KP, 13, w_process, Kz, Kz, b_process,
                                                hbuf, nullptr, nullptr, nullptr, nullptr);
    k_bn<<<dim3(Tz), blk, 0, stream>>>(hbuf, bn_gamma, bn_beta, hbn);
    k_gemm<1><<<dim3(100, 1), blk, 0, stream>>>(hbn, KP, 13, w_compress, K2, Kz, b_compress,
                                                xc_pad, o_xc, nullptr, nullptr, nullptr);
    k_gemm<2><<<dim3(100, 7), blk, 0, stream>>>(xc_pad, K2P, 1, w_unzip, Kz, K2, b_unzip,
                                                z1, nullptr, nullptr, nullptr, nullptr);
    k_gemm<3><<<dim3(100, 7), blk, 0, stream>>>(z1, KP, 13, w_unprocess, Kz, Kz, b_unprocess,
                                                zb, nullptr, index_ws, nullptr, o_recon);
    k_gemm<4><<<dim3(100, 122), blk, 0, stream>>>(zb, KP, 13, w_rest, RESTz, Kz, b_rest,
                                                  nullptr, nullptr, nullptr, rest_pos, o_recon);
    k_mask<<<dim3(Bz * Tz), dim3(256), 0, stream>>>(index_ws, o_mask);
}

// Round 15
// 650.618 us; speedup vs baseline: 1.8155x; 1.8155x over previous
//
#include <hip/hip_runtime.h>

#define Bz 32
#define Tz 200
#define Rz 8192
#define Kz 409
#define KP 416
#define K2 20
#define K2P 32
#define RESTz 7783

typedef __bf16 bf16x8 __attribute__((ext_vector_type(8)));
typedef float f32x4 __attribute__((ext_vector_type(4)));

// ---------------- pad+cast f32 weight [N][Kd] -> bf16 [Npad][Kpad] ------------
__launch_bounds__(256)
__global__ void k_padcast(const float* __restrict__ src, __bf16* __restrict__ dst,
                          int N, int Kd, int Npad, int Kpad) {
    int i = blockIdx.x * 256 + threadIdx.x;
    int total = Npad * Kpad;
    if (i >= total) return;
    int r = i / Kpad, c = i - r * Kpad;
    float v = (r < N && c < Kd) ? src[(size_t)r * Kd + c] : 0.f;
    dst[i] = (__bf16)v;
}

// ---------------- pass 1: norms, scores, border mask (f32 out) ----------------
// R14 (bit-exact, DO NOT TOUCH): XLA-GPU column-reduction emulation.
__launch_bounds__(256)
__global__ void k_stats(const float* __restrict__ x, const float* __restrict__ w_proj,
                        const float* __restrict__ b_proj,
                        float* __restrict__ invnrm, float* __restrict__ score,
                        int* __restrict__ bordany, float* __restrict__ border_out) {
    const int b = blockIdx.y;
    const int c = blockIdx.x * 256 + threadIdx.x;
    const float* xp = x + (size_t)b * Tz * Rz + c;
    float* bp = border_out + (size_t)b * Tz * Rz + c;
    float p[32];
#pragma unroll
    for (int y = 0; y < 32; ++y) p[y] = 0.f;
    int nn = 0;
    for (int k = 0; k < 7; ++k) {
        const int tbase = k * 32;
#pragma unroll
        for (int y = 0; y < 32; ++y) {
            const int t = tbase + y;
            if (t < Tz) {
                float v = xp[(size_t)t * Rz];
                bool isn = (v != v);
                nn |= isn ? 1 : 0;
                float val = isn ? 0.f : v;
                bp[(size_t)t * Rz] = isn ? 1.0f : 0.0f;
                p[y] = __fadd_rn(p[y], __fmul_rn(val, val));
            }
        }
    }
#pragma unroll
    for (int off = 16; off > 0; off >>= 1)
#pragma unroll
        for (int y = 0; y < 16; ++y)
            if (y < off) p[y] = __fadd_rn(p[y], p[y + off]);
    const float ss = p[0];
    const float nv = fmaxf(__fsqrt_rn(ss), 1e-12f);
    float q[32];
#pragma unroll
    for (int y = 0; y < 32; ++y) q[y] = 0.f;
    for (int k = 0; k < 7; ++k) {
        const int tbase = k * 32;
#pragma unroll
        for (int y = 0; y < 32; ++y) {
            const int t = tbase + y;
            if (t < Tz) {
                float v = xp[(size_t)t * Rz];
                float val = (v != v) ? 0.f : v;
                float xn = __fdiv_rn(val, nv);
                float e = __fmul_rn(xn, w_proj[t]);
                q[y] = __fadd_rn(q[y], e);
            }
        }
    }
#pragma unroll
    for (int off = 16; off > 0; off >>= 1)
#pragma unroll
        for (int y = 0; y < 16; ++y)
            if (y < off) q[y] = __fadd_rn(q[y], q[y + off]);
    float sc = __fadd_rn(q[0], b_proj[0]);
    if (nn) sc = -10000.f;
    invnrm[(size_t)b * Rz + c] = __fdiv_rn(1.0f, nv);
    score[(size_t)b * Rz + c] = sc;
    bordany[(size_t)b * Rz + c] = nn;
}

// ---------------- top-k (radix select + bitonic order) + rest positions -------
__launch_bounds__(256)
__global__ void k_topk(const float* __restrict__ score, const int* __restrict__ bordany,
                       int* __restrict__ index_ws, int* __restrict__ rest_pos,
                       float* __restrict__ o_index) {
    const int b = blockIdx.x;
    const int tid = threadIdx.x;
    __shared__ unsigned su[Rz];
    __shared__ unsigned hist[256];
    __shared__ unsigned ckey[512];
    __shared__ unsigned cidx[512];
    __shared__ unsigned cnum;
    __shared__ unsigned sh_prefix;
    __shared__ int sh_need;
    __shared__ int scnt[256];

    for (int i = tid; i < Rz; i += 256) {
        unsigned u = __float_as_uint(score[(size_t)b * Rz + i]);
        u = (u & 0x80000000u) ? ~u : (u | 0x80000000u);
        su[i] = u;
    }
    __syncthreads();

    unsigned prefix = 0u, pmask = 0u;
    int need = Kz;
    for (int byte = 3; byte >= 0; --byte) {
        const int sh = byte * 8;
        hist[tid] = 0u;
        __syncthreads();
        for (int i = tid; i < Rz; i += 256) {
            unsigned u = su[i];
            if ((u & pmask) == prefix) atomicAdd(&hist[(u >> sh) & 255u], 1u);
        }
        __syncthreads();
        if (tid == 0) {
            int acc = 0, bsel = 255;
            for (int v = 255; v >= 0; --v) {
                int h = (int)hist[v];
                if (acc + h >= need) { bsel = v; break; }
                acc += h;
            }
            sh_need = need - acc;
            sh_prefix = prefix | ((unsigned)bsel << sh);
        }
        __syncthreads();
        prefix = sh_prefix;
        need = sh_need;
        pmask |= (0xFFu << sh);
        __syncthreads();
    }
    const unsigned Tval = prefix;

    if (tid == 0) cnum = 0u;
    __syncthreads();
    for (int i = tid; i < Rz; i += 256) {
        unsigned u = su[i];
        if (u >= Tval) {
            unsigned p = atomicAdd(&cnum, 1u);
            if (p < 512u) { ckey[p] = u; cidx[p] = (unsigned)i; }
        }
    }
    __syncthreads();
    const int cn = (cnum < 512u) ? (int)cnum : 512;
    for (int i = tid; i < 512; i += 256)
        if (i >= cn) { ckey[i] = 0u; cidx[i] = 0xFFFFFFFFu; }
    __syncthreads();

    // bitonic sort 512: (key desc, idx asc)
    for (int kk = 2; kk <= 512; kk <<= 1) {
        for (int j = kk >> 1; j > 0; j >>= 1) {
            const int i = ((tid & ~(j - 1)) << 1) | (tid & (j - 1));
            const int l = i | j;
            unsigned ka = ckey[i], kb = ckey[l];
            unsigned ia = cidx[i], ib = cidx[l];
            bool a_after_b = (ka < kb) || (ka == kb && ia > ib);
            bool b_after_a = (kb < ka) || (kb == ka && ib > ia);
            bool desc = ((i & kk) == 0);
            bool dosw = desc ? a_after_b : b_after_a;
            if (dosw) { ckey[i] = kb; ckey[l] = ka; cidx[i] = ib; cidx[l] = ia; }
            __syncthreads();
        }
    }

    for (int i = tid; i < Kz; i += 256) {
        int idx = (int)(cidx[i] & 8191u);
        index_ws[b * Kz + i] = idx;
        o_index[(size_t)b * Kz + i] = (float)idx;
    }
    __syncthreads();
    for (int i = tid; i < Rz; i += 256)
        su[i] = (bordany[(size_t)b * Rz + i] != 0) ? 1u : 0u;
    __syncthreads();
    for (int i = tid; i < Kz; i += 256) su[cidx[i] & 8191u] = 1u;
    __syncthreads();
    int cnt = 0;
    {
        const int base = tid * 32;
#pragma unroll
        for (int o = 0; o < 32; ++o) cnt += (su[base + o] == 0u) ? 1 : 0;
    }
    scnt[tid] = cnt;
    __syncthreads();
    for (int offp = 1; offp < 256; offp <<= 1) {
        int add = (tid >= offp) ? scnt[tid - offp] : 0;
        __syncthreads();
        scnt[tid] += add;
        __syncthreads();
    }
    const int total_un = scnt[255];
    int run = scnt[tid] - cnt;
    const int base = tid * 32;
    for (int o = 0; o < 32; ++o) {
        const int c = base + o;
        const bool un = (su[c] == 0u);
        int pos = un ? run : (total_un + (c - run));
        if (un) run++;
        if (pos < RESTz) rest_pos[b * RESTz + pos] = c;
    }
}

// ---------------- gather selected, normalized columns -> bf16 [6400][KP] ------
__launch_bounds__(256)
__global__ void k_gather(const float* __restrict__ x, const float* __restrict__ invnrm,
                         const int* __restrict__ index_ws, __bf16* __restrict__ x_topk) {
    const int m = blockIdx.x;
    const int b = m / Tz;
    const float* xrow = x + (size_t)m * Rz;
    for (int kk = threadIdx.x; kk < KP; kk += 256) {
        float val = 0.f;
        if (kk < Kz) {
            const unsigned idx = (unsigned)index_ws[b * Kz + kk] & 8191u;
            float v = xrow[idx];
            if (v != v) v = 0.f;
            val = __fmul_rn(v, invnrm[(size_t)b * Rz + idx]);
        }
        x_topk[(size_t)m * KP + kk] = (__bf16)val;
    }
}

// ---------------- BatchNorm over (b,k) per t (bf16 in, bf16 out) --------------
__launch_bounds__(256)
__global__ void k_bn(const __bf16* __restrict__ h, const float* __restrict__ gamma,
                     const float* __restrict__ beta, __bf16* __restrict__ hbn) {
    const int t = blockIdx.x;
    const int tid = threadIdx.x;
    float s = 0.f, s2 = 0.f;
    for (int i = tid; i < Bz * Kz; i += 256) {
        int b = i / Kz, j = i - b * Kz;
        float v = (float)h[(size_t)(b * Tz + t) * KP + j];
        s += v;
        s2 += v * v;
    }
    for (int off = 32; off > 0; off >>= 1) {
        s += __shfl_down(s, off);
        s2 += __shfl_down(s2, off);
    }
    __shared__ float rs[4], rs2[4];
    __shared__ float sc_sh, sf_sh;
    const int wid = tid >> 6;
    if ((tid & 63) == 0) { rs[wid] = s; rs2[wid] = s2; }
    __syncthreads();
    if (tid == 0) {
        float S = rs[0] + rs[1] + rs[2] + rs[3];
        float S2 = rs2[0] + rs2[1] + rs2[2] + rs2[3];
        const float invN = 1.f / (float)(Bz * Kz);
        float mu = S * invN;
        float var = S2 * invN - mu * mu;
        float rstd = rsqrtf(var + 1e-5f);
        float scl = gamma[t] * rstd;
        sc_sh = scl;
        sf_sh = beta[t] - mu * scl;
    }
    __syncthreads();
    const float scl = sc_sh, sft = sf_sh;
    for (int i = tid; i < Bz * KP; i += 256) {
        int b = i / KP, j = i - b * KP;
        float outv = 0.f;
        if (j < Kz) {
            float v = (float)h[(size_t)(b * Tz + t) * KP + j];
            outv = v * scl + sft;
        }
        hbn[(size_t)(b * Tz + t) * KP + j] = (__bf16)outv;
    }
}

// ---------------- dense mask writer (f32): mask[b,t,r] = sel[b][r] ------------
__launch_bounds__(256)
__global__ void k_mask(const int* __restrict__ index_ws, float* __restrict__ o_mask) {
    const int bt = blockIdx.x;
    const int b = bt / Tz;
    const int tid = threadIdx.x;
    __shared__ unsigned bm[256];
    bm[tid] = 0u;
    __syncthreads();
    for (int i = tid; i < Kz; i += 256) {
        unsigned idx = (unsigned)index_ws[b * Kz + i] & 8191u;
        atomicOr(&bm[idx >> 5], 1u << (idx & 31u));
    }
    __syncthreads();
    const unsigned bits = bm[tid];
    float* dst = o_mask + (size_t)bt * Rz + tid * 32;
#pragma unroll
    for (int g = 0; g < 8; ++g) {
        float4 v;
        v.x = ((bits >> (g * 4 + 0)) & 1u) ? 1.0f : 0.0f;
        v.y = ((bits >> (g * 4 + 1)) & 1u) ? 1.0f : 0.0f;
        v.z = ((bits >> (g * 4 + 2)) & 1u) ? 1.0f : 0.0f;
        v.w = ((bits >> (g * 4 + 3)) & 1u) ? 1.0f : 0.0f;
        *(float4*)(dst + g * 4) = v;
    }
}

// ---- R15: 128x128-tile MFMA GEMM, bf16 A and pre-cast bf16 B (padded) --------
// 256 thr = 4 waves (2x2), each wave 64x64 = 4x4 frags of 16x16x32. BK=32.
// LDS rows padded to 56 bf16 (112B, 16B-aligned, <=2-way bank conflicts).
template <int EPI>
__launch_bounds__(256)
__global__ void k_gemm(const __bf16* __restrict__ A, int lda, int ksteps,
                       const __bf16* __restrict__ Wb, int ldb,
                       const float* __restrict__ bias,
                       __bf16* __restrict__ b_out,
                       float* __restrict__ o_xc,
                       const int* __restrict__ index_ws,
                       const int* __restrict__ rest_pos,
                       float* __restrict__ o_recon) {
    __shared__ __bf16 As[128][56];
    __shared__ __bf16 Bs[128][56];
    const int m0 = blockIdx.x * 128;
    const int n0 = blockIdx.y * 128;
    const int tid = threadIdx.x;
    const int lane = tid & 63;
    const int wid = tid >> 6;
    const int wm = wid >> 1, wn = wid & 1;   // wave tile: 64x64
    const int srow = tid >> 2;               // 0..63
    const int seg = (tid & 3) * 8;           // 0,8,16,24
    const int fr = lane & 15;
    const int fg = lane >> 4;                // 0..3
    f32x4 acc[4][4];
#pragma unroll
    for (int i = 0; i < 4; ++i)
#pragma unroll
        for (int j = 0; j < 4; ++j) {
            f32x4 z = {0.f, 0.f, 0.f, 0.f};
            acc[i][j] = z;
        }

    const __bf16* ap0 = A + (size_t)(m0 + srow) * lda + seg;
    const __bf16* ap1 = A + (size_t)(m0 + srow + 64) * lda + seg;
    const __bf16* bp0 = Wb + (size_t)(n0 + srow) * ldb + seg;
    const __bf16* bp1 = Wb + (size_t)(n0 + srow + 64) * ldb + seg;

    for (int s = 0; s < ksteps; ++s) {
        const int k0 = s * 32;
        bf16x8 a0 = *(const bf16x8*)(ap0 + k0);
        bf16x8 a1 = *(const bf16x8*)(ap1 + k0);
        bf16x8 b0 = *(const bf16x8*)(bp0 + k0);
        bf16x8 b1 = *(const bf16x8*)(bp1 + k0);
        __syncthreads();
        *(bf16x8*)&As[srow][seg] = a0;
        *(bf16x8*)&As[srow + 64][seg] = a1;
        *(bf16x8*)&Bs[srow][seg] = b0;
        *(bf16x8*)&Bs[srow + 64][seg] = b1;
        __syncthreads();
        bf16x8 af[4], bf[4];
#pragma unroll
        for (int mi = 0; mi < 4; ++mi)
            af[mi] = *(const bf16x8*)&As[wm * 64 + mi * 16 + fr][fg * 8];
#pragma unroll
        for (int ni = 0; ni < 4; ++ni)
            bf[ni] = *(const bf16x8*)&Bs[wn * 64 + ni * 16 + fr][fg * 8];
#pragma unroll
        for (int mi = 0; mi < 4; ++mi)
#pragma unroll
            for (int ni = 0; ni < 4; ++ni)
                acc[mi][ni] = __builtin_amdgcn_mfma_f32_16x16x32_bf16(af[mi], bf[ni],
                                                                      acc[mi][ni], 0, 0, 0);
    }

#pragma unroll
    for (int mi = 0; mi < 4; ++mi)
#pragma unroll
        for (int ni = 0; ni < 4; ++ni)
#pragma unroll
            for (int rr = 0; rr < 4; ++rr) {
                const int gm = m0 + wm * 64 + mi * 16 + fg * 4 + rr;
                const int gn = n0 + wn * 64 + ni * 16 + fr;
                const float v = acc[mi][ni][rr];
                if constexpr (EPI == 0) {
                    if (gn < KP) {
                        float val = (gn < Kz) ? (v + bias[gn]) : 0.f;
                        b_out[(size_t)gm * KP + gn] = (__bf16)val;
                    }
                } else if constexpr (EPI == 1) {
                    if (gn < K2P) {
                        float val = (gn < K2) ? (v + bias[gn]) : 0.f;
                        if (gn < K2) o_xc[(size_t)gm * K2 + gn] = val;
                        b_out[(size_t)gm * K2P + gn] = (__bf16)val;
                    }
                } else if constexpr (EPI == 2) {
                    if (gn < KP) {
                        float val = (gn < Kz) ? (v + bias[gn]) : 0.f;
                        b_out[(size_t)gm * KP + gn] = (__bf16)val;
                    }
                } else if constexpr (EPI == 3) {
                    if (gn < KP) {
                        float val = (gn < Kz) ? (v + bias[gn]) : 0.f;
                        b_out[(size_t)gm * KP + gn] = (__bf16)val;
                        if (gn < Kz) {
                            const int bb = gm / Tz;
                            const unsigned col = (unsigned)index_ws[bb * Kz + gn] & 8191u;
                            o_recon[(size_t)gm * Rz + col] = val;
                        }
                    }
                } else {
                    if (gn < RESTz) {
                        const float val = v + bias[gn];
                        const int bb = gm / Tz;
                        const unsigned col = (unsigned)rest_pos[bb * RESTz + gn] & 8191u;
                        o_recon[(size_t)gm * Rz + col] = val;
                    }
                }
            }
}

extern "C" void kernel_launch(void* const* d_in, const int* in_sizes, int n_in,
                              void* d_out, int out_size, void* d_ws, size_t ws_size,
                              hipStream_t stream) {
    (void)in_sizes; (void)n_in; (void)out_size;
    const float* x           = (const float*)d_in[0];
    const float* w_proj      = (const float*)d_in[1];
    const float* b_proj      = (const float*)d_in[2];
    const float* w_process   = (const float*)d_in[3];
    const float* b_process   = (const float*)d_in[4];
    const float* bn_gamma    = (const float*)d_in[5];
    const float* bn_beta     = (const float*)d_in[6];
    const float* w_compress  = (const float*)d_in[7];
    const float* b_compress  = (const float*)d_in[8];
    const float* w_unzip     = (const float*)d_in[9];
    const float* b_unzip     = (const float*)d_in[10];
    const float* w_unprocess = (const float*)d_in[11];
    const float* b_unprocess = (const float*)d_in[12];
    const float* w_rest      = (const float*)d_in[13];
    const float* b_rest      = (const float*)d_in[14];

    float* out = (float*)d_out;
    float* o_recon  = out;
    float* o_xc     = o_recon + (size_t)Bz * Tz * Rz;
    float* o_mask   = o_xc + (size_t)Bz * Tz * K2;
    float* o_border = o_mask + (size_t)Bz * Tz * Rz;
    float* o_index  = o_border + (size_t)Bz * Tz * Rz;

    const size_t SLOT = ((size_t)Bz * Tz * KP * 2 + 255) & ~(size_t)255;
    const size_t IDXB = ((size_t)Bz * Kz * 4 + 255) & ~(size_t)255;
    const size_t RESB = ((size_t)Bz * RESTz * 4 + 255) & ~(size_t)255;
    const size_t WPB  = ((size_t)512 * KP * 2 + 255) & ~(size_t)255;   // wp_b / wup_b
    const size_t WZB  = ((size_t)512 * K2P * 2 + 255) & ~(size_t)255;  // wz_b
    const size_t WCB  = ((size_t)128 * KP * 2 + 255) & ~(size_t)255;   // wc_b
    const size_t need = 3 * SLOT + IDXB + RESB + 2 * WPB + WZB + WCB;
    if (ws_size < need) return;

    char* ws = (char*)d_ws;
    __bf16* S1 = (__bf16*)(ws);
    __bf16* S2 = (__bf16*)(ws + SLOT);
    __bf16* S3 = (__bf16*)(ws + 2 * SLOT);
    int* index_ws = (int*)(ws + 3 * SLOT);
    int* rest_pos = (int*)(ws + 3 * SLOT + IDXB);
    __bf16* wp_b  = (__bf16*)(ws + 3 * SLOT + IDXB + RESB);
    __bf16* wup_b = (__bf16*)(ws + 3 * SLOT + IDXB + RESB + WPB);
    __bf16* wz_b  = (__bf16*)(ws + 3 * SLOT + IDXB + RESB + 2 * WPB);
    __bf16* wc_b  = (__bf16*)(ws + 3 * SLOT + IDXB + RESB + 2 * WPB + WZB);
    // wrest_b overlays S1+S2 (both dead after k_gemm<3>): 7808*416*2 = 6.5MB < 2*SLOT
    __bf16* wrest_b = (__bf16*)(ws);

    float* invnrm = (float*)S2;
    float* score  = invnrm + (size_t)Bz * Rz;
    int*   bordany = (int*)(score + (size_t)Bz * Rz);

    __bf16* x_topk = S1;
    __bf16* hbuf   = S2;
    __bf16* hbn    = S3;
    __bf16* xc_pad = S2;
    __bf16* z1     = S1;
    __bf16* zb     = S3;

    auto PC = [&](const float* src, __bf16* dst, int N, int Kd, int Npad, int Kpad) {
        int total = Npad * Kpad;
        k_padcast<<<dim3((total + 255) / 256), dim3(256), 0, stream>>>(src, dst, N, Kd, Npad, Kpad);
    };
    PC(w_process, wp_b, Kz, Kz, 512, KP);
    PC(w_unprocess, wup_b, Kz, Kz, 512, KP);
    PC(w_unzip, wz_b, Kz, K2, 512, K2P);
    PC(w_compress, wc_b, K2, Kz, 128, KP);

    k_stats<<<dim3(Rz / 256, Bz), dim3(256), 0, stream>>>(x, w_proj, b_proj, invnrm, score,
                                                          bordany, o_border);
    k_topk<<<dim3(Bz), dim3(256), 0, stream>>>(score, bordany, index_ws, rest_pos, o_index);
    k_gather<<<dim3(Bz * Tz), dim3(256), 0, stream>>>(x, invnrm, index_ws, x_topk);

    dim3 blk(256);
    k_gemm<0><<<dim3(50, 4), blk, 0, stream>>>(x_topk, KP, 13, wp_b, KP, b_process,
                                               hbuf, nullptr, nullptr, nullptr, nullptr);
    k_bn<<<dim3(Tz), blk, 0, stream>>>(hbuf, bn_gamma, bn_beta, hbn);
    k_gemm<1><<<dim3(50, 1), blk, 0, stream>>>(hbn, KP, 13, wc_b, KP, b_compress,
                                               xc_pad, o_xc, nullptr, nullptr, nullptr);
    k_gemm<2><<<dim3(50, 4), blk, 0, stream>>>(xc_pad, K2P, 1, wz_b, K2P, b_unzip,
                                               z1, nullptr, nullptr, nullptr, nullptr);
    k_gemm<3><<<dim3(50, 4), blk, 0, stream>>>(z1, KP, 13, wup_b, KP, b_unprocess,
                                               zb, nullptr, index_ws, nullptr, o_recon);
    // S1/S2 dead from here: cast w_rest into the overlay, then the big GEMM.
    PC(w_rest, wrest_b, RESTz, Kz, 7808, KP);
    k_gemm<4><<<dim3(50, 61), blk, 0, stream>>>(zb, KP, 13, wrest_b, KP, b_rest,
                                                nullptr, nullptr, nullptr, rest_pos, o_recon);
    k_mask<<<dim3(Bz * Tz), dim3(256), 0, stream>>>(index_ws, o_mask);
}

// Round 16
// 604.724 us; speedup vs baseline: 1.9532x; 1.0759x over previous
//
#include <hip/hip_runtime.h>

#define Bz 32
#define Tz 200
#define Rz 8192
#define Kz 409
#define KP 416
#define K2 20
#define K2P 32
#define RESTz 7783

typedef __bf16 bf16x8 __attribute__((ext_vector_type(8)));
typedef float f32x4 __attribute__((ext_vector_type(4)));

// ---------------- pad+cast f32 weight [N][Kd] -> bf16 [Npad][Kpad] ------------
__launch_bounds__(256)
__global__ void k_padcast(const float* __restrict__ src, __bf16* __restrict__ dst,
                          int N, int Kd, int Npad, int Kpad) {
    int i = blockIdx.x * 256 + threadIdx.x;
    int total = Npad * Kpad;
    if (i >= total) return;
    int r = i / Kpad, c = i - r * Kpad;
    float v = (r < N && c < Kd) ? src[(size_t)r * Kd + c] : 0.f;
    dst[i] = (__bf16)v;
}

// ---------------- pass 1: norms, scores, border mask (f32 out) ----------------
// R14 (bit-exact, DO NOT TOUCH): XLA-GPU column-reduction emulation.
__launch_bounds__(256)
__global__ void k_stats(const float* __restrict__ x, const float* __restrict__ w_proj,
                        const float* __restrict__ b_proj,
                        float* __restrict__ invnrm, float* __restrict__ score,
                        int* __restrict__ bordany, float* __restrict__ border_out) {
    const int b = blockIdx.y;
    const int c = blockIdx.x * 256 + threadIdx.x;
    const float* xp = x + (size_t)b * Tz * Rz + c;
    float* bp = border_out + (size_t)b * Tz * Rz + c;
    float p[32];
#pragma unroll
    for (int y = 0; y < 32; ++y) p[y] = 0.f;
    int nn = 0;
    for (int k = 0; k < 7; ++k) {
        const int tbase = k * 32;
#pragma unroll
        for (int y = 0; y < 32; ++y) {
            const int t = tbase + y;
            if (t < Tz) {
                float v = xp[(size_t)t * Rz];
                bool isn = (v != v);
                nn |= isn ? 1 : 0;
                float val = isn ? 0.f : v;
                bp[(size_t)t * Rz] = isn ? 1.0f : 0.0f;
                p[y] = __fadd_rn(p[y], __fmul_rn(val, val));
            }
        }
    }
#pragma unroll
    for (int off = 16; off > 0; off >>= 1)
#pragma unroll
        for (int y = 0; y < 16; ++y)
            if (y < off) p[y] = __fadd_rn(p[y], p[y + off]);
    const float ss = p[0];
    const float nv = fmaxf(__fsqrt_rn(ss), 1e-12f);
    float q[32];
#pragma unroll
    for (int y = 0; y < 32; ++y) q[y] = 0.f;
    for (int k = 0; k < 7; ++k) {
        const int tbase = k * 32;
#pragma unroll
        for (int y = 0; y < 32; ++y) {
            const int t = tbase + y;
            if (t < Tz) {
                float v = xp[(size_t)t * Rz];
                float val = (v != v) ? 0.f : v;
                float xn = __fdiv_rn(val, nv);
                float e = __fmul_rn(xn, w_proj[t]);
                q[y] = __fadd_rn(q[y], e);
            }
        }
    }
#pragma unroll
    for (int off = 16; off > 0; off >>= 1)
#pragma unroll
        for (int y = 0; y < 16; ++y)
            if (y < off) q[y] = __fadd_rn(q[y], q[y + off]);
    float sc = __fadd_rn(q[0], b_proj[0]);
    if (nn) sc = -10000.f;
    invnrm[(size_t)b * Rz + c] = __fdiv_rn(1.0f, nv);
    score[(size_t)b * Rz + c] = sc;
    bordany[(size_t)b * Rz + c] = nn;
}

// ---------------- top-k (radix select + bitonic order) + rest positions -------
// R16: 1024 threads; parallel suffix-sum bucket select.
__launch_bounds__(1024)
__global__ void k_topk(const float* __restrict__ score, const int* __restrict__ bordany,
                       int* __restrict__ index_ws, int* __restrict__ rest_pos,
                       float* __restrict__ o_index) {
    const int b = blockIdx.x;
    const int tid = threadIdx.x;
    __shared__ unsigned su[Rz];
    __shared__ unsigned hist[256];
    __shared__ unsigned sfx[256];
    __shared__ unsigned ckey[512];
    __shared__ unsigned cidx[512];
    __shared__ unsigned cnum;
    __shared__ unsigned sh_prefix;
    __shared__ int sh_need;
    __shared__ int scnt[1024];

    for (int i = tid; i < Rz; i += 1024) {
        unsigned u = __float_as_uint(score[(size_t)b * Rz + i]);
        u = (u & 0x80000000u) ? ~u : (u | 0x80000000u);
        su[i] = u;
    }
    __syncthreads();

    unsigned prefix = 0u, pmask = 0u;
    int need = Kz;
    for (int byte = 3; byte >= 0; --byte) {
        const int sh = byte * 8;
        if (tid < 256) hist[tid] = 0u;
        __syncthreads();
        for (int i = tid; i < Rz; i += 1024) {
            unsigned u = su[i];
            if ((u & pmask) == prefix) atomicAdd(&hist[(u >> sh) & 255u], 1u);
        }
        __syncthreads();
        if (tid < 256) sfx[tid] = hist[tid];
        __syncthreads();
        for (int off = 1; off < 256; off <<= 1) {
            unsigned add = 0u;
            if (tid < 256 && tid + off < 256) add = sfx[tid + off];
            __syncthreads();
            if (tid < 256) sfx[tid] += add;
            __syncthreads();
        }
        // sfx[v] = count of entries with bucket >= v. bsel = unique v with
        // sfx[v] >= need and sfx[v+1] < need  (matches serial top-down scan).
        if (tid < 256) {
            unsigned above = (tid == 255) ? 0u : sfx[tid + 1];
            if (sfx[tid] >= (unsigned)need && above < (unsigned)need) {
                sh_need = need - (int)above;
                sh_prefix = prefix | ((unsigned)tid << sh);
            }
        }
        __syncthreads();
        prefix = sh_prefix;
        need = sh_need;
        pmask |= (0xFFu << sh);
        __syncthreads();
    }
    const unsigned Tval = prefix;

    if (tid == 0) cnum = 0u;
    __syncthreads();
    for (int i = tid; i < Rz; i += 1024) {
        unsigned u = su[i];
        if (u >= Tval) {
            unsigned p = atomicAdd(&cnum, 1u);
            if (p < 512u) { ckey[p] = u; cidx[p] = (unsigned)i; }
        }
    }
    __syncthreads();
    const int cn = (cnum < 512u) ? (int)cnum : 512;
    for (int i = tid; i < 512; i += 1024)
        if (i >= cn) { ckey[i] = 0u; cidx[i] = 0xFFFFFFFFu; }
    __syncthreads();

    // bitonic sort 512: (key desc, idx asc); comparators on tid<256
    for (int kk = 2; kk <= 512; kk <<= 1) {
        for (int j = kk >> 1; j > 0; j >>= 1) {
            if (tid < 256) {
                const int i = ((tid & ~(j - 1)) << 1) | (tid & (j - 1));
                const int l = i | j;
                unsigned ka = ckey[i], kb = ckey[l];
                unsigned ia = cidx[i], ib = cidx[l];
                bool a_after_b = (ka < kb) || (ka == kb && ia > ib);
                bool b_after_a = (kb < ka) || (kb == ka && ib > ia);
                bool desc = ((i & kk) == 0);
                bool dosw = desc ? a_after_b : b_after_a;
                if (dosw) { ckey[i] = kb; ckey[l] = ka; cidx[i] = ib; cidx[l] = ia; }
            }
            __syncthreads();
        }
    }

    for (int i = tid; i < Kz; i += 1024) {
        int idx = (int)(cidx[i] & 8191u);
        index_ws[b * Kz + i] = idx;
        o_index[(size_t)b * Kz + i] = (float)idx;
    }
    __syncthreads();
    for (int i = tid; i < Rz; i += 1024)
        su[i] = (bordany[(size_t)b * Rz + i] != 0) ? 1u : 0u;
    __syncthreads();
    for (int i = tid; i < Kz; i += 1024) su[cidx[i] & 8191u] = 1u;
    __syncthreads();
    int cnt = 0;
    {
        const int base = tid * 8;
#pragma unroll
        for (int o = 0; o < 8; ++o) cnt += (su[base + o] == 0u) ? 1 : 0;
    }
    scnt[tid] = cnt;
    __syncthreads();
    for (int offp = 1; offp < 1024; offp <<= 1) {
        int add = (tid >= offp) ? scnt[tid - offp] : 0;
        __syncthreads();
        scnt[tid] += add;
        __syncthreads();
    }
    const int total_un = scnt[1023];
    int run = scnt[tid] - cnt;
    const int base = tid * 8;
    for (int o = 0; o < 8; ++o) {
        const int c = base + o;
        const bool un = (su[c] == 0u);
        int pos = un ? run : (total_un + (c - run));
        if (un) run++;
        if (pos < RESTz) rest_pos[b * RESTz + pos] = c;
    }
}

// ---------------- gather selected, normalized columns -> bf16 [6400][KP] ------
__launch_bounds__(256)
__global__ void k_gather(const float* __restrict__ x, const float* __restrict__ invnrm,
                         const int* __restrict__ index_ws, __bf16* __restrict__ x_topk) {
    const int m = blockIdx.x;
    const int b = m / Tz;
    const float* xrow = x + (size_t)m * Rz;
    for (int kk = threadIdx.x; kk < KP; kk += 256) {
        float val = 0.f;
        if (kk < Kz) {
            const unsigned idx = (unsigned)index_ws[b * Kz + kk] & 8191u;
            float v = xrow[idx];
            if (v != v) v = 0.f;
            val = __fmul_rn(v, invnrm[(size_t)b * Rz + idx]);
        }
        x_topk[(size_t)m * KP + kk] = (__bf16)val;
    }
}

// ---------------- BatchNorm over (b,k) per t (bf16 in, bf16 out) --------------
__launch_bounds__(256)
__global__ void k_bn(const __bf16* __restrict__ h, const float* __restrict__ gamma,
                     const float* __restrict__ beta, __bf16* __restrict__ hbn) {
    const int t = blockIdx.x;
    const int tid = threadIdx.x;
    float s = 0.f, s2 = 0.f;
    for (int i = tid; i < Bz * Kz; i += 256) {
        int b = i / Kz, j = i - b * Kz;
        float v = (float)h[(size_t)(b * Tz + t) * KP + j];
        s += v;
        s2 += v * v;
    }
    for (int off = 32; off > 0; off >>= 1) {
        s += __shfl_down(s, off);
        s2 += __shfl_down(s2, off);
    }
    __shared__ float rs[4], rs2[4];
    __shared__ float sc_sh, sf_sh;
    const int wid = tid >> 6;
    if ((tid & 63) == 0) { rs[wid] = s; rs2[wid] = s2; }
    __syncthreads();
    if (tid == 0) {
        float S = rs[0] + rs[1] + rs[2] + rs[3];
        float S2 = rs2[0] + rs2[1] + rs2[2] + rs2[3];
        const float invN = 1.f / (float)(Bz * Kz);
        float mu = S * invN;
        float var = S2 * invN - mu * mu;
        float rstd = rsqrtf(var + 1e-5f);
        float scl = gamma[t] * rstd;
        sc_sh = scl;
        sf_sh = beta[t] - mu * scl;
    }
    __syncthreads();
    const float scl = sc_sh, sft = sf_sh;
    for (int i = tid; i < Bz * KP; i += 256) {
        int b = i / KP, j = i - b * KP;
        float outv = 0.f;
        if (j < Kz) {
            float v = (float)h[(size_t)(b * Tz + t) * KP + j];
            outv = v * scl + sft;
        }
        hbn[(size_t)(b * Tz + t) * KP + j] = (__bf16)outv;
    }
}

// ---------------- dense mask writer (f32): mask[b,t,r] = sel[b][r] ------------
__launch_bounds__(256)
__global__ void k_mask(const int* __restrict__ index_ws, float* __restrict__ o_mask) {
    const int bt = blockIdx.x;
    const int b = bt / Tz;
    const int tid = threadIdx.x;
    __shared__ unsigned bm[256];
    bm[tid] = 0u;
    __syncthreads();
    for (int i = tid; i < Kz; i += 256) {
        unsigned idx = (unsigned)index_ws[b * Kz + i] & 8191u;
        atomicOr(&bm[idx >> 5], 1u << (idx & 31u));
    }
    __syncthreads();
    const unsigned bits = bm[tid];
    float* dst = o_mask + (size_t)bt * Rz + tid * 32;
#pragma unroll
    for (int g = 0; g < 8; ++g) {
        float4 v;
        v.x = ((bits >> (g * 4 + 0)) & 1u) ? 1.0f : 0.0f;
        v.y = ((bits >> (g * 4 + 1)) & 1u) ? 1.0f : 0.0f;
        v.z = ((bits >> (g * 4 + 2)) & 1u) ? 1.0f : 0.0f;
        v.w = ((bits >> (g * 4 + 3)) & 1u) ? 1.0f : 0.0f;
        *(float4*)(dst + g * 4) = v;
    }
}

// ---- R16: 128x128-tile MFMA GEMM with global_load_lds(16B) into linear LDS ---
// LDS [128][32] bf16 (8KB per operand). Chunk j (16 rows x 32 cols = 1KB):
// lane l loads row j*16+(l>>2), cols (l&3)*8.. -> LDS base_j + l*16 exactly.
// Wave w stages chunks {w, w+4} of A and B. 2 barriers per K-step.
template <int EPI>
__launch_bounds__(256)
__global__ void k_gemm(const __bf16* __restrict__ A, int lda, int ksteps,
                       const __bf16* __restrict__ Wb, int ldb,
                       const float* __restrict__ bias,
                       __bf16* __restrict__ b_out,
                       float* __restrict__ o_xc,
                       const int* __restrict__ index_ws,
                       const int* __restrict__ rest_pos,
                       float* __restrict__ o_recon) {
    __shared__ __bf16 As[128][32];
    __shared__ __bf16 Bs[128][32];
    const int m0 = blockIdx.x * 128;
    const int n0 = blockIdx.y * 128;
    const int tid = threadIdx.x;
    const int lane = tid & 63;
    const int wid = tid >> 6;
    const int wm = wid >> 1, wn = wid & 1;   // wave tile: 64x64
    const int r0 = lane >> 2;                // 0..15 row-in-chunk
    const int sg = (lane & 3) * 8;           // 0,8,16,24
    const int fr = lane & 15;
    const int fg = lane >> 4;                // 0..3
    f32x4 acc[4][4];
#pragma unroll
    for (int i = 0; i < 4; ++i)
#pragma unroll
        for (int j = 0; j < 4; ++j) {
            f32x4 z = {0.f, 0.f, 0.f, 0.f};
            acc[i][j] = z;
        }

    const int ca = wid * 16 + r0;        // chunk wid rows
    const int cb = (wid + 4) * 16 + r0;  // chunk wid+4 rows
    const __bf16* gA0 = A + (size_t)(m0 + ca) * lda + sg;
    const __bf16* gA1 = A + (size_t)(m0 + cb) * lda + sg;
    const __bf16* gB0 = Wb + (size_t)(n0 + ca) * ldb + sg;
    const __bf16* gB1 = Wb + (size_t)(n0 + cb) * ldb + sg;
    __bf16* lA0 = &As[wid * 16][0];
    __bf16* lA1 = &As[(wid + 4) * 16][0];
    __bf16* lB0 = &Bs[wid * 16][0];
    __bf16* lB1 = &Bs[(wid + 4) * 16][0];

    for (int s = 0; s < ksteps; ++s) {
        const int k0 = s * 32;
        __syncthreads();   // previous iteration's reads complete before overwrite
        __builtin_amdgcn_global_load_lds(gA0 + k0, lA0, 16, 0, 0);
        __builtin_amdgcn_global_load_lds(gA1 + k0, lA1, 16, 0, 0);
        __builtin_amdgcn_global_load_lds(gB0 + k0, lB0, 16, 0, 0);
        __builtin_amdgcn_global_load_lds(gB1 + k0, lB1, 16, 0, 0);
        __syncthreads();   // vmcnt(0) drained before barrier -> data visible
        bf16x8 af[4], bf[4];
#pragma unroll
        for (int mi = 0; mi < 4; ++mi)
            af[mi] = *(const bf16x8*)&As[wm * 64 + mi * 16 + fr][fg * 8];
#pragma unroll
        for (int ni = 0; ni < 4; ++ni)
            bf[ni] = *(const bf16x8*)&Bs[wn * 64 + ni * 16 + fr][fg * 8];
#pragma unroll
        for (int mi = 0; mi < 4; ++mi)
#pragma unroll
            for (int ni = 0; ni < 4; ++ni)
                acc[mi][ni] = __builtin_amdgcn_mfma_f32_16x16x32_bf16(af[mi], bf[ni],
                                                                      acc[mi][ni], 0, 0, 0);
    }

#pragma unroll
    for (int mi = 0; mi < 4; ++mi)
#pragma unroll
        for (int ni = 0; ni < 4; ++ni)
#pragma unroll
            for (int rr = 0; rr < 4; ++rr) {
                const int gm = m0 + wm * 64 + mi * 16 + fg * 4 + rr;
                const int gn = n0 + wn * 64 + ni * 16 + fr;
                const float v = acc[mi][ni][rr];
                if constexpr (EPI == 0) {
                    if (gn < KP) {
                        float val = (gn < Kz) ? (v + bias[gn]) : 0.f;
                        b_out[(size_t)gm * KP + gn] = (__bf16)val;
                    }
                } else if constexpr (EPI == 1) {
                    if (gn < K2P) {
                        float val = (gn < K2) ? (v + bias[gn]) : 0.f;
                        if (gn < K2) o_xc[(size_t)gm * K2 + gn] = val;
                        b_out[(size_t)gm * K2P + gn] = (__bf16)val;
                    }
                } else if constexpr (EPI == 2) {
                    if (gn < KP) {
                        float val = (gn < Kz) ? (v + bias[gn]) : 0.f;
                        b_out[(size_t)gm * KP + gn] = (__bf16)val;
                    }
                } else if constexpr (EPI == 3) {
                    if (gn < KP) {
                        float val = (gn < Kz) ? (v + bias[gn]) : 0.f;
                        b_out[(size_t)gm * KP + gn] = (__bf16)val;
                        if (gn < Kz) {
                            const int bb = gm / Tz;
                            const unsigned col = (unsigned)index_ws[bb * Kz + gn] & 8191u;
                            o_recon[(size_t)gm * Rz + col] = val;
                        }
                    }
                } else {
                    if (gn < RESTz) {
                        const float val = v + bias[gn];
                        const int bb = gm / Tz;
                        const unsigned col = (unsigned)rest_pos[bb * RESTz + gn] & 8191u;
                        o_recon[(size_t)gm * Rz + col] = val;
                    }
                }
            }
}

extern "C" void kernel_launch(void* const* d_in, const int* in_sizes, int n_in,
                              void* d_out, int out_size, void* d_ws, size_t ws_size,
                              hipStream_t stream) {
    (void)in_sizes; (void)n_in; (void)out_size;
    const float* x           = (const float*)d_in[0];
    const float* w_proj      = (const float*)d_in[1];
    const float* b_proj      = (const float*)d_in[2];
    const float* w_process   = (const float*)d_in[3];
    const float* b_process   = (const float*)d_in[4];
    const float* bn_gamma    = (const float*)d_in[5];
    const float* bn_beta     = (const float*)d_in[6];
    const float* w_compress  = (const float*)d_in[7];
    const float* b_compress  = (const float*)d_in[8];
    const float* w_unzip     = (const float*)d_in[9];
    const float* b_unzip     = (const float*)d_in[10];
    const float* w_unprocess = (const float*)d_in[11];
    const float* b_unprocess = (const float*)d_in[12];
    const float* w_rest      = (const float*)d_in[13];
    const float* b_rest      = (const float*)d_in[14];

    float* out = (float*)d_out;
    float* o_recon  = out;
    float* o_xc     = o_recon + (size_t)Bz * Tz * Rz;
    float* o_mask   = o_xc + (size_t)Bz * Tz * K2;
    float* o_border = o_mask + (size_t)Bz * Tz * Rz;
    float* o_index  = o_border + (size_t)Bz * Tz * Rz;

    const size_t SLOT = ((size_t)Bz * Tz * KP * 2 + 255) & ~(size_t)255;
    const size_t IDXB = ((size_t)Bz * Kz * 4 + 255) & ~(size_t)255;
    const size_t RESB = ((size_t)Bz * RESTz * 4 + 255) & ~(size_t)255;
    const size_t WPB  = ((size_t)512 * KP * 2 + 255) & ~(size_t)255;
    const size_t WZB  = ((size_t)512 * K2P * 2 + 255) & ~(size_t)255;
    const size_t WCB  = ((size_t)128 * KP * 2 + 255) & ~(size_t)255;
    const size_t need = 3 * SLOT + IDXB + RESB + 2 * WPB + WZB + WCB;
    if (ws_size < need) return;

    char* ws = (char*)d_ws;
    __bf16* S1 = (__bf16*)(ws);
    __bf16* S2 = (__bf16*)(ws + SLOT);
    __bf16* S3 = (__bf16*)(ws + 2 * SLOT);
    int* index_ws = (int*)(ws + 3 * SLOT);
    int* rest_pos = (int*)(ws + 3 * SLOT + IDXB);
    __bf16* wp_b  = (__bf16*)(ws + 3 * SLOT + IDXB + RESB);
    __bf16* wup_b = (__bf16*)(ws + 3 * SLOT + IDXB + RESB + WPB);
    __bf16* wz_b  = (__bf16*)(ws + 3 * SLOT + IDXB + RESB + 2 * WPB);
    __bf16* wc_b  = (__bf16*)(ws + 3 * SLOT + IDXB + RESB + 2 * WPB + WZB);
    // wrest_b overlays S1+S2 (dead after k_gemm<3>): 7808*416*2 = 6.5MB < 2*SLOT
    __bf16* wrest_b = (__bf16*)(ws);

    float* invnrm = (float*)S2;
    float* score  = invnrm + (size_t)Bz * Rz;
    int*   bordany = (int*)(score + (size_t)Bz * Rz);

    __bf16* x_topk = S1;
    __bf16* hbuf   = S2;
    __bf16* hbn    = S3;
    __bf16* xc_pad = S2;
    __bf16* z1     = S1;
    __bf16* zb     = S3;

    auto PC = [&](const float* src, __bf16* dst, int N, int Kd, int Npad, int Kpad) {
        int total = Npad * Kpad;
        k_padcast<<<dim3((total + 255) / 256), dim3(256), 0, stream>>>(src, dst, N, Kd, Npad, Kpad);
    };
    PC(w_process, wp_b, Kz, Kz, 512, KP);
    PC(w_unprocess, wup_b, Kz, Kz, 512, KP);
    PC(w_unzip, wz_b, Kz, K2, 512, K2P);
    PC(w_compress, wc_b, K2, Kz, 128, KP);

    k_stats<<<dim3(Rz / 256, Bz), dim3(256), 0, stream>>>(x, w_proj, b_proj, invnrm, score,
                                                          bordany, o_border);
    k_topk<<<dim3(Bz), dim3(1024), 0, stream>>>(score, bordany, index_ws, rest_pos, o_index);
    k_gather<<<dim3(Bz * Tz), dim3(256), 0, stream>>>(x, invnrm, index_ws, x_topk);

    dim3 blk(256);
    k_gemm<0><<<dim3(50, 4), blk, 0, stream>>>(x_topk, KP, 13, wp_b, KP, b_process,
                                               hbuf, nullptr, nullptr, nullptr, nullptr);
    k_bn<<<dim3(Tz), blk, 0, stream>>>(hbuf, bn_gamma, bn_beta, hbn);
    k_gemm<1><<<dim3(50, 1), blk, 0, stream>>>(hbn, KP, 13, wc_b, KP, b_compress,
                                               xc_pad, o_xc, nullptr, nullptr, nullptr);
    k_gemm<2><<<dim3(50, 4), blk, 0, stream>>>(xc_pad, K2P, 1, wz_b, K2P, b_unzip,
                                               z1, nullptr, nullptr, nullptr, nullptr);
    k_gemm<3><<<dim3(50, 4), blk, 0, stream>>>(z1, KP, 13, wup_b, KP, b_unprocess,
                                               zb, nullptr, index_ws, nullptr, o_recon);
    // S1/S2 dead from here: cast w_rest into the overlay, then the big GEMM.
    PC(w_rest, wrest_b, RESTz, Kz, 7808, KP);
    k_gemm<4><<<dim3(50, 61), blk, 0, stream>>>(zb, KP, 13, wrest_b, KP, b_rest,
                                                nullptr, nullptr, nullptr, rest_pos, o_recon);
    k_mask<<<dim3(Bz * Tz), dim3(256), 0, stream>>>(index_ws, o_mask);
}